// Round 1
// baseline (5101.501 us; speedup 1.0000x reference)
//
#include <hip/hip_runtime.h>
#include <hip/hip_bf16.h>

#define VOCAB  50000
#define HIDDEN 256
#define BATCH  64
#define SEQ    2048

__device__ __forceinline__ float tanh_fast(float x) {
    // tanh(x) = 1 - 2/(exp(2x)+1); exact at +-inf overflow, plenty of precision vs 1.5e-2 threshold
    float e = __expf(2.0f * x);
    return 1.0f - 2.0f / (e + 1.0f);
}

// ---------------------------------------------------------------------------
// Phase 1: x_pre[row,h] = bias[h] + sum_d embed[x[row],d] * Wx[h,d]
// row in [0, B*S). 16 rows per block, 256 threads (thread j = output col h=j).
// Embedding rows staged in LDS (uniform broadcast reads); Wx row j streamed
// from global per-thread (sequential 16B walk -> L1-friendly, Wx is L2-hot).
// ---------------------------------------------------------------------------
__global__ void xpre_kernel(const int* __restrict__ x,
                            const float* __restrict__ embed,
                            const float* __restrict__ Wx,
                            const float* __restrict__ bias,
                            float* __restrict__ out) {
    const int tid  = threadIdx.x;
    const long row0 = (long)blockIdx.x * 16;

    __shared__ int toks[16];
    __shared__ __align__(16) float e[16][HIDDEN];

    if (tid < 16) toks[tid] = x[row0 + tid];
    __syncthreads();

    #pragma unroll
    for (int r = 0; r < 16; ++r) {
        e[r][tid] = embed[(long)toks[r] * HIDDEN + tid];
    }
    __syncthreads();

    float acc[16];
    const float bj = bias[tid];
    #pragma unroll
    for (int r = 0; r < 16; ++r) acc[r] = bj;

    const float* wrow = Wx + (long)tid * HIDDEN;

    #pragma unroll 4
    for (int d0 = 0; d0 < HIDDEN; d0 += 4) {
        const float4 w = *(const float4*)(wrow + d0);
        #pragma unroll
        for (int r = 0; r < 16; ++r) {
            const float4 ev = *(const float4*)&e[r][d0];   // uniform broadcast
            float a = acc[r];
            a = fmaf(w.x, ev.x, a);
            a = fmaf(w.y, ev.y, a);
            a = fmaf(w.z, ev.z, a);
            a = fmaf(w.w, ev.w, a);
            acc[r] = a;
        }
    }

    #pragma unroll
    for (int r = 0; r < 16; ++r) {
        out[(row0 + r) * HIDDEN + tid] = acc[r];   // coalesced 1KB per r
    }
}

// ---------------------------------------------------------------------------
// Phase 2: sequential scan. One block per batch element (64 blocks, 256 thr).
// Thread j owns output column j; W_h row j lives in 256 VGPRs (64 float4).
// h double-buffered in LDS -> exactly one barrier per timestep.
// x_pre rows are read from d_out and overwritten in-place with h states.
// ---------------------------------------------------------------------------
__global__ __launch_bounds__(256, 1)
void rnn_scan_kernel(const float* __restrict__ Wh,
                     float* __restrict__ out) {
    const int b = blockIdx.x;
    const int j = threadIdx.x;

    // Load W_h row j into registers (one-time, 256 KB total per WG from L2/L3)
    float4 w[64];
    {
        const float* wrow = Wh + (long)j * HIDDEN;
        #pragma unroll
        for (int k = 0; k < 64; ++k) w[k] = *(const float4*)(wrow + 4 * k);
    }

    __shared__ __align__(16) float hbuf[2][HIDDEN];
    hbuf[0][j] = 0.0f;                    // h0 = 0

    float* row = out + (long)b * SEQ * HIDDEN;
    float xp = row[j];                    // x_pre at t=0 (prefetched)
    __syncthreads();

    int cur = 0;
    for (int t = 0; t < SEQ; ++t) {
        // prefetch next step's x_pre (row t+1 still holds x_pre)
        float xpn = 0.0f;
        if (t + 1 < SEQ) xpn = row[(t + 1) * HIDDEN + j];

        const float* hb = hbuf[cur];
        float a0 = 0.f, a1 = 0.f, a2 = 0.f, a3 = 0.f;
        float a4 = 0.f, a5 = 0.f, a6 = 0.f, a7 = 0.f;
        #pragma unroll
        for (int k = 0; k < 32; ++k) {
            const float4 h0 = *(const float4*)(hb + 4 * k);        // broadcast
            const float4 h1 = *(const float4*)(hb + 128 + 4 * k);  // broadcast
            const float4 w0 = w[k];
            const float4 w1 = w[k + 32];
            a0 = fmaf(w0.x, h0.x, a0);
            a1 = fmaf(w0.y, h0.y, a1);
            a2 = fmaf(w0.z, h0.z, a2);
            a3 = fmaf(w0.w, h0.w, a3);
            a4 = fmaf(w1.x, h1.x, a4);
            a5 = fmaf(w1.y, h1.y, a5);
            a6 = fmaf(w1.z, h1.z, a6);
            a7 = fmaf(w1.w, h1.w, a7);
        }
        const float acc = xp + (((a0 + a1) + (a2 + a3)) + ((a4 + a5) + (a6 + a7)));
        const float h = tanh_fast(acc);

        row[t * HIDDEN + j] = h;          // overwrite consumed x_pre row
        hbuf[cur ^ 1][j] = h;
        __syncthreads();                  // one barrier per step (double buffer)
        cur ^= 1;
        xp = xpn;
    }
}

extern "C" void kernel_launch(void* const* d_in, const int* in_sizes, int n_in,
                              void* d_out, int out_size, void* d_ws, size_t ws_size,
                              hipStream_t stream) {
    const int*   x     = (const int*)d_in[0];
    const float* embed = (const float*)d_in[1];
    const float* Wx    = (const float*)d_in[2];
    const float* Wxb   = (const float*)d_in[3];
    const float* Wh    = (const float*)d_in[4];
    float* out = (float*)d_out;

    // Phase 1: x_pre for all (b,s) rows -> d_out
    const int nrows = BATCH * SEQ;                 // 131072
    xpre_kernel<<<nrows / 16, 256, 0, stream>>>(x, embed, Wx, Wxb, out);

    // Phase 2: per-batch sequential scan, overwrites x_pre with h states
    rnn_scan_kernel<<<BATCH, 256, 0, stream>>>(Wh, out);
}

// Round 2
// 1899.784 us; speedup vs baseline: 2.6853x; 2.6853x over previous
//
#include <hip/hip_runtime.h>
#include <hip/hip_bf16.h>

#define VOCAB  50000
#define HIDDEN 256
#define BATCH  64
#define SEQ    2048
#define QPAD   68   // 64 floats per quarter + 4-float pad (kills 4-way bank conflict)

__device__ __forceinline__ float tanh_fast(float x) {
    // tanh(x) = 1 - 2/(exp(2x)+1); exact at +-inf, plenty of precision vs 1.5e-2 threshold
    float e = __expf(2.0f * x);
    return 1.0f - 2.0f / (e + 1.0f);
}

// ---------------------------------------------------------------------------
// Phase 1: x_pre[row,h] = bias[h] + sum_d embed[x[row],d] * Wx[h,d]
// 16 rows per block, 256 threads (thread j = output col h=j). Unchanged.
// ---------------------------------------------------------------------------
__global__ void xpre_kernel(const int* __restrict__ x,
                            const float* __restrict__ embed,
                            const float* __restrict__ Wx,
                            const float* __restrict__ bias,
                            float* __restrict__ out) {
    const int tid  = threadIdx.x;
    const long row0 = (long)blockIdx.x * 16;

    __shared__ int toks[16];
    __shared__ __align__(16) float e[16][HIDDEN];

    if (tid < 16) toks[tid] = x[row0 + tid];
    __syncthreads();

    #pragma unroll
    for (int r = 0; r < 16; ++r) {
        e[r][tid] = embed[(long)toks[r] * HIDDEN + tid];
    }
    __syncthreads();

    float acc[16];
    const float bj = bias[tid];
    #pragma unroll
    for (int r = 0; r < 16; ++r) acc[r] = bj;

    const float* wrow = Wx + (long)tid * HIDDEN;

    #pragma unroll 4
    for (int d0 = 0; d0 < HIDDEN; d0 += 4) {
        const float4 w = *(const float4*)(wrow + d0);
        #pragma unroll
        for (int r = 0; r < 16; ++r) {
            const float4 ev = *(const float4*)&e[r][d0];   // uniform broadcast
            float a = acc[r];
            a = fmaf(w.x, ev.x, a);
            a = fmaf(w.y, ev.y, a);
            a = fmaf(w.z, ev.z, a);
            a = fmaf(w.w, ev.w, a);
            acc[r] = a;
        }
    }

    #pragma unroll
    for (int r = 0; r < 16; ++r) {
        out[(row0 + r) * HIDDEN + tid] = acc[r];   // coalesced 1KB per r
    }
}

// ---------------------------------------------------------------------------
// Phase 2: sequential scan. One block of 1024 threads per batch element.
// Thread (j = tid>>2, q = tid&3): output column j, h-quarter q.
// Weights: 16 NAMED float4 (64 VGPRs) -> compiler must keep them in registers.
// h in LDS, quarter-padded layout [4][QPAD]; double-buffered, 1 barrier/step.
// 4 partials reduced with 2x shfl_xor within each 4-lane group.
// ---------------------------------------------------------------------------
__global__ __launch_bounds__(1024, 4)
void rnn_scan_kernel(const float* __restrict__ Wh,
                     float* __restrict__ out) {
    const int b   = blockIdx.x;
    const int tid = threadIdx.x;
    const int j   = tid >> 2;   // output column [0,256)
    const int q   = tid & 3;    // h quarter

    // 16 named float4 = this thread's 64 weights Wh[j][q*64 .. q*64+63]
    const float* wrow = Wh + (size_t)j * HIDDEN + (q << 6);
#define LDW(K) const float4 w##K = *(const float4*)(wrow + 4 * (K));
    LDW(0)  LDW(1)  LDW(2)  LDW(3)  LDW(4)  LDW(5)  LDW(6)  LDW(7)
    LDW(8)  LDW(9)  LDW(10) LDW(11) LDW(12) LDW(13) LDW(14) LDW(15)
#undef LDW

    __shared__ __align__(16) float hbuf[2][4 * QPAD];
    if (tid < 4 * QPAD) hbuf[0][tid] = 0.0f;     // h0 = 0 (incl. pads)

    float* row = out + (size_t)b * SEQ * HIDDEN;
    float xp = row[j];                           // x_pre at t=0 (prefetch)
    const int wslot = (j >> 6) * QPAD + (j & 63);
    const int qoff  = q * QPAD;

    __syncthreads();

    float* hcur = hbuf[0];
    float* hnxt = hbuf[1];

    for (int t = 0; t < SEQ; ++t) {
        // prefetch next step's x_pre (row t+1 still holds x_pre)
        float xpn = 0.0f;
        if (t + 1 < SEQ) xpn = row[(size_t)(t + 1) * HIDDEN + j];

        const float* hb = hcur + qoff;
        float a0 = 0.f, a1 = 0.f, a2 = 0.f, a3 = 0.f;
#define STEPK(K) { const float4 hv = *(const float4*)(hb + 4 * (K));   \
        a0 = fmaf(w##K.x, hv.x, a0); a1 = fmaf(w##K.y, hv.y, a1);      \
        a2 = fmaf(w##K.z, hv.z, a2); a3 = fmaf(w##K.w, hv.w, a3); }
        STEPK(0)  STEPK(1)  STEPK(2)  STEPK(3)
        STEPK(4)  STEPK(5)  STEPK(6)  STEPK(7)
        STEPK(8)  STEPK(9)  STEPK(10) STEPK(11)
        STEPK(12) STEPK(13) STEPK(14) STEPK(15)
#undef STEPK
        float s = (a0 + a1) + (a2 + a3);
        s += __shfl_xor(s, 1);                  // reduce across the 4 q-lanes
        s += __shfl_xor(s, 2);
        const float h = tanh_fast(xp + s);

        if (q == 0) {
            hnxt[wslot] = h;                    // 16 consecutive slots per wave
            row[(size_t)t * HIDDEN + j] = h;    // 64B contiguous per wave
        }
        __syncthreads();                        // one barrier per step
        float* tmp = hcur; hcur = hnxt; hnxt = tmp;
        xp = xpn;
    }
}

extern "C" void kernel_launch(void* const* d_in, const int* in_sizes, int n_in,
                              void* d_out, int out_size, void* d_ws, size_t ws_size,
                              hipStream_t stream) {
    const int*   x     = (const int*)d_in[0];
    const float* embed = (const float*)d_in[1];
    const float* Wx    = (const float*)d_in[2];
    const float* Wxb   = (const float*)d_in[3];
    const float* Wh    = (const float*)d_in[4];
    float* out = (float*)d_out;

    // Phase 1: x_pre for all (b,s) rows -> d_out
    const int nrows = BATCH * SEQ;                 // 131072
    xpre_kernel<<<nrows / 16, 256, 0, stream>>>(x, embed, Wx, Wxb, out);

    // Phase 2: per-batch sequential scan, overwrites x_pre with h states
    rnn_scan_kernel<<<BATCH, 1024, 0, stream>>>(Wh, out);
}